// Round 1
// 474.517 us; speedup vs baseline: 1.1085x; 1.1085x over previous
//
#include <hip/hip_runtime.h>
#include <hip/hip_bf16.h>
#include <cstdint>
#include <cstddef>

#define BB 8
#define SS 1024
#define DDIM 768
#define FFF 3072
#define EE 8

typedef __attribute__((ext_vector_type(8))) short short8;
typedef __attribute__((ext_vector_type(4))) float f32x4;
typedef __attribute__((ext_vector_type(4))) unsigned short us4;

__device__ __forceinline__ unsigned short f2bf(float f) {
  unsigned u = __float_as_uint(f);
  u += 0x7FFFu + ((u >> 16) & 1u);
  return (unsigned short)(u >> 16);
}

__device__ __forceinline__ void async_ld16(const void* g, void* l) {
  __builtin_amdgcn_global_load_lds(
      (const __attribute__((address_space(1))) void*)g,
      (__attribute__((address_space(3))) void*)l, 16, 0, 0);
}

// ---------------- fused prep: tcast W1 | tcast W2 | cast x | pooled ----------------
__global__ __launch_bounds__(256) void prep_kernel(
    const float* __restrict__ W1, const float* __restrict__ W2,
    const float* __restrict__ x,
    unsigned short* __restrict__ w1t, unsigned short* __restrict__ w2t,
    unsigned short* __restrict__ xb, float* __restrict__ pooled) {
  __shared__ unsigned short tile[64 * 66 + 32];
  int blk = blockIdx.x;
  int t = threadIdx.x;
  if (blk < 9216) {
    const float* src; unsigned short* dst; int R, C, r0, c0;
    if (blk < 4608) {
      int e = blk / 576, rem = blk % 576;           // 12 r-tiles x 48 c-tiles
      r0 = (rem / 48) * 64; c0 = (rem % 48) * 64;
      src = W1 + (size_t)e * DDIM * FFF; dst = w1t + (size_t)e * FFF * DDIM;
      R = DDIM; C = FFF;
    } else {
      int b2 = blk - 4608;
      int e = b2 / 576, rem = b2 % 576;             // 48 r-tiles x 12 c-tiles
      r0 = (rem / 12) * 64; c0 = (rem % 12) * 64;
      src = W2 + (size_t)e * FFF * DDIM; dst = w2t + (size_t)e * DDIM * FFF;
      R = FFF; C = DDIM;
    }
    int row = t >> 4, c4 = (t & 15) * 4;
#pragma unroll
    for (int it = 0; it < 4; it++) {
      int r = row + it * 16;
      float4 v = *(const float4*)&src[(size_t)(r0 + r) * C + c0 + c4];
      us4 u; u[0] = f2bf(v.x); u[1] = f2bf(v.y); u[2] = f2bf(v.z); u[3] = f2bf(v.w);
      *(us4*)&tile[r * 66 + c4] = u;
    }
    __syncthreads();
    int seg = (t & 7) * 8;
#pragma unroll
    for (int it = 0; it < 2; it++) {
      int crow = it * 32 + (t >> 3);
      short8 u;
#pragma unroll
      for (int j = 0; j < 8; j++) u[j] = (short)tile[(seg + j) * 66 + crow];
      *(short8*)&dst[(size_t)(c0 + crow) * R + r0 + seg] = u;
    }
  } else if (blk < 12288) {
    size_t i = ((size_t)(blk - 9216) * 256 + t) * 8;
    float4 a = *(const float4*)&x[i];
    float4 b = *(const float4*)&x[i + 4];
    short8 u;
    u[0] = f2bf(a.x); u[1] = f2bf(a.y); u[2] = f2bf(a.z); u[3] = f2bf(a.w);
    u[4] = f2bf(b.x); u[5] = f2bf(b.y); u[6] = f2bf(b.z); u[7] = f2bf(b.w);
    *(short8*)&xb[i] = u;
  } else {
    float* red = (float*)tile;
    int blk2 = blk - 12288;
    int b = blk2 / 24, d0 = (blk2 % 24) * 32;
    int dl = t & 31, sg = t >> 5;
    const float* p = x + ((size_t)b * SS + sg) * DDIM + d0 + dl;
    float s = 0.f;
#pragma unroll 4
    for (int i = 0; i < SS / 8; i++) s += p[(size_t)i * 8 * DDIM];
    red[t] = s;
    __syncthreads();
    if (t < 32) {
      float acc = red[t];
#pragma unroll
      for (int g = 1; g < 8; g++) acc += red[g * 32 + t];
      pooled[b * DDIM + d0 + t] = acc * (1.f / SS);
    }
  }
}

// ---------------- router ----------------
__global__ void router_kernel(const float* __restrict__ pooled,
                              const float* __restrict__ text,
                              const float* __restrict__ rw,
                              const float* __restrict__ rb,
                              float* __restrict__ probs_out,
                              int* __restrict__ topi,
                              float* __restrict__ topv) {
  __shared__ float lg[BB * EE];
  int t = threadIdx.x;
  int be = t >> 4, part = t & 15;
  int b = be >> 3, e = be & 7;
  const float* pb = pooled + b * DDIM;
  const float* tb = text + b * DDIM;
  float acc = 0.f;
  int i0 = part * 96;
  for (int i = i0; i < i0 + 96; i++) {
    float f = (i < DDIM) ? pb[i] : tb[i - DDIM];
    acc += f * rw[i * EE + e];
  }
#pragma unroll
  for (int o = 8; o >= 1; o >>= 1) acc += __shfl_xor(acc, o);
  if (part == 0) lg[be] = acc + rb[e];
  __syncthreads();
  if (t < BB) {
    float p[EE];
    float mx = -1e30f;
    for (int e2 = 0; e2 < EE; e2++) { p[e2] = lg[t * EE + e2]; mx = fmaxf(mx, p[e2]); }
    float s = 0.f;
    for (int e2 = 0; e2 < EE; e2++) { p[e2] = expf(p[e2] - mx); s += p[e2]; }
    float inv = 1.f / s;
    for (int e2 = 0; e2 < EE; e2++) { p[e2] *= inv; probs_out[t * EE + e2] = p[e2]; }
    int j0 = 0; float v0 = p[0];
    for (int e2 = 1; e2 < EE; e2++) if (p[e2] > v0) { v0 = p[e2]; j0 = e2; }
    int j1 = -1; float v1 = -1e30f;
    for (int e2 = 0; e2 < EE; e2++) if (e2 != j0 && p[e2] > v1) { v1 = p[e2]; j1 = e2; }
    topi[t * 2] = j0; topi[t * 2 + 1] = j1;
    topv[t * 2] = v0; topv[t * 2 + 1] = v1;
  }
}

// ---------------- pipelined 256x256 GEMM, BK=64, counted vmcnt ----------------
// LDS per stage (ushorts): A0 [0,8192) A1 [8192,16384) B0 [16384,24576) B1 [24576,32768)
// Stage stride 32768 ush (64KB); total 128KB, 1 block/CU, 8 waves (2M x 4N).
// Per K-tile: 4 phases x 16 MFMA. Issues: P1 A0(t+1)->other stage, P2 A1(t+1),
// P3 B0(t+2)->current stage (B slots freed by end-P1 barrier), P4 B1(t+2).
// vmcnt(4) at tile start = allow B0/B1(t+1) (4 insts) outstanding; everything
// older (all of tile t) must have landed. Last tile drains with vmcnt(0).
template <int LDK, int NT, int TPP, bool GELU>
__global__ __launch_bounds__(512, 2) void gemm_pipe(
    const unsigned short* __restrict__ Abase,
    const unsigned short* __restrict__ Bbase,
    const float* __restrict__ b1,
    const int* __restrict__ topi,
    const float* __restrict__ topv,
    unsigned short* __restrict__ hout_,
    float* __restrict__ yout_) {
  int wg = (blockIdx.x & 7) * (TPP * 2) + (blockIdx.x >> 3);  // XCD swizzle (nwg%8==0)
  int pair = wg / TPP;
  int rem = wg - pair * TPP;
  int M0 = (rem >> 2) * 256;
  int N0 = (rem & 3) * 256;
  int e = topi[pair];
  const unsigned short* A = Abase + (size_t)e * ((size_t)DDIM * FFF);
  const unsigned short* B = GELU ? Bbase + (size_t)(pair >> 1) * SS * DDIM
                                 : Bbase + (size_t)pair * SS * FFF;

  __shared__ unsigned short sm[65536];
  int t = threadIdx.x;
  int lane = t & 63, wave = t >> 6;
  int wm = wave >> 2, wn = wave & 3;

  // staging: thread t loads 16B; row sr (64 rows/unit), chunk c4 of 8 (x16B=128B row)
  int sr = t >> 3, c4 = t & 7;
  int gch = (c4 ^ (sr & 7)) * 8;  // pre-swizzled global source (T2)
  const unsigned short* gA = A + (size_t)(M0 + sr) * LDK + gch;
  const unsigned short* gB = B + (size_t)(N0 + sr) * LDK + gch;
  unsigned short* lds_t = sm + t * 8;  // = wave-uniform base + lane*16B (linear dest)

#define ISSUE2(gp, rofs, kk, uofs)                                    \
  do {                                                                \
    async_ld16((gp) + (size_t)(rofs) * LDK + (kk), lds_t + (uofs));   \
    async_ld16((gp) + (size_t)((rofs) + 64) * LDK + (kk),             \
               lds_t + (uofs) + 4096);                                \
  } while (0)

  // prologue: tile0 (A0,A1,B0,B1)->st0, then tile1 B halves ->st1
  ISSUE2(gA, 0, 0, 0);
  ISSUE2(gA, 128, 0, 8192);
  ISSUE2(gB, 0, 0, 16384);
  ISSUE2(gB, 128, 0, 24576);
  ISSUE2(gB, 0, 64, 32768 + 16384);
  ISSUE2(gB, 128, 64, 32768 + 24576);

  f32x4 acc[8][4];
#pragma unroll
  for (int i = 0; i < 8; i++)
#pragma unroll
    for (int j = 0; j < 4; j++) acc[i][j] = (f32x4){0.f, 0.f, 0.f, 0.f};

  int l15 = lane & 15, lg = lane >> 4, lx = lane & 7;
  int ch0 = (lg ^ lx) * 8;        // k-step 0 chunk (swizzled read)
  int ch1 = ((4 + lg) ^ lx) * 8;  // k-step 1 chunk
  int aoff = wm * 8192 + l15 * 64;
  int boff = 16384 + (wn >> 1) * 8192 + ((wn & 1) * 64 + l15) * 64;

#define PHASE(p, so_)                                                                      \
  do {                                                                                     \
    short8 a0k0 = *(const short8*)&sm[(so_) + aoff + (2 * (p)) * 1024 + ch0];              \
    short8 a0k1 = *(const short8*)&sm[(so_) + aoff + (2 * (p)) * 1024 + ch1];              \
    short8 a1k0 = *(const short8*)&sm[(so_) + aoff + (2 * (p) + 1) * 1024 + ch0];          \
    short8 a1k1 = *(const short8*)&sm[(so_) + aoff + (2 * (p) + 1) * 1024 + ch1];          \
    __builtin_amdgcn_s_setprio(1);                                                         \
    _Pragma("unroll") for (int j = 0; j < 4; j++) {                                        \
      acc[2 * (p)][j] =                                                                    \
          __builtin_amdgcn_mfma_f32_16x16x32_bf16(a0k0, bf[j][0], acc[2 * (p)][j], 0, 0, 0);   \
      acc[2 * (p)][j] =                                                                    \
          __builtin_amdgcn_mfma_f32_16x16x32_bf16(a0k1, bf[j][1], acc[2 * (p)][j], 0, 0, 0);   \
      acc[2 * (p) + 1][j] =                                                                \
          __builtin_amdgcn_mfma_f32_16x16x32_bf16(a1k0, bf[j][0], acc[2 * (p) + 1][j], 0, 0, 0); \
      acc[2 * (p) + 1][j] =                                                                \
          __builtin_amdgcn_mfma_f32_16x16x32_bf16(a1k1, bf[j][1], acc[2 * (p) + 1][j], 0, 0, 0); \
    }                                                                                      \
    __builtin_amdgcn_s_setprio(0);                                                         \
  } while (0)

#pragma unroll 2
  for (int kt = 0; kt < NT; kt++) {
    int so = (kt & 1) << 15;
    int sn = so ^ 32768;
    int kn = (kt + 1) * 64;
    int k2 = (kt + 2) * 64;
    // ---- P1 ----
    if (kt + 1 < NT)
      asm volatile("s_waitcnt vmcnt(4)" ::: "memory");
    else
      asm volatile("s_waitcnt vmcnt(0)" ::: "memory");
    __builtin_amdgcn_s_barrier();
    asm volatile("" ::: "memory");
    if (kt + 1 < NT) ISSUE2(gA, 0, kn, sn);
    short8 bf[4][2];
#pragma unroll
    for (int j = 0; j < 4; j++) {
      bf[j][0] = *(const short8*)&sm[so + boff + j * 1024 + ch0];
      bf[j][1] = *(const short8*)&sm[so + boff + j * 1024 + ch1];
    }
    PHASE(0, so);
    asm volatile("" ::: "memory");
    __builtin_amdgcn_s_barrier();   // frees this stage's B slots (bf cached in regs)
    asm volatile("" ::: "memory");
    // ---- P2 ----
    if (kt + 1 < NT) ISSUE2(gA, 128, kn, sn + 8192);
    PHASE(1, so);
    // ---- P3 ----
    if (kt + 2 < NT) ISSUE2(gB, 0, k2, so + 16384);
    PHASE(2, so);
    // ---- P4 ----
    if (kt + 2 < NT) ISSUE2(gB, 128, k2, so + 24576);
    PHASE(3, so);
  }
#undef PHASE
#undef ISSUE2

  int fb0 = M0 + wm * 128 + lg * 4;
  int sb0 = N0 + wn * 64 + l15;
  if constexpr (GELU) {
    float tv = topv[pair];
    unsigned short* ho = hout_ + (size_t)pair * SS * FFF;
    f32x4 bias[8];
#pragma unroll
    for (int i = 0; i < 8; i++)
      bias[i] = *(const f32x4*)&b1[e * FFF + fb0 + i * 16];
#pragma unroll
    for (int j = 0; j < 4; j++) {
      int s = sb0 + j * 16;
#pragma unroll
      for (int i = 0; i < 8; i++) {
        us4 u;
#pragma unroll
        for (int r = 0; r < 4; r++) {
          float v = acc[i][j][r] + bias[i][r];
          float v2 = v * v;
          float u2 = v * (1.5957691216057308f + 0.07135481627f * v2);
          float ex = __expf(-u2);
          float g = v / (1.f + ex);
          u[r] = f2bf(g * tv);
        }
        *(us4*)&ho[(size_t)s * FFF + fb0 + i * 16] = u;
      }
    }
  } else {
    float* yo = yout_ + (size_t)pair * SS * DDIM;
#pragma unroll
    for (int j = 0; j < 4; j++) {
      int s = sb0 + j * 16;
#pragma unroll
      for (int i = 0; i < 8; i++)
        *(f32x4*)&yo[(size_t)s * DDIM + fb0 + i * 16] = acc[i][j];
    }
  }
}

// ---------------- LayerNorm + residual ----------------
__global__ void ln_kernel(const float* __restrict__ x,
                          const float* __restrict__ y,
                          const float* __restrict__ b2,
                          const int* __restrict__ topi,
                          const float* __restrict__ topv,
                          const float* __restrict__ gamma,
                          const float* __restrict__ beta,
                          float* __restrict__ out) {
  int wave = threadIdx.x >> 6, lane = threadIdx.x & 63;
  int row = blockIdx.x * 4 + wave;
  int b = row >> 10, s = row & 1023;
  int e0 = topi[b * 2], e1 = topi[b * 2 + 1];
  float tv0 = topv[b * 2], tv1 = topv[b * 2 + 1];
  const float* y0r = y + ((size_t)(b * 2) * SS + s) * DDIM;
  const float* y1r = y + ((size_t)(b * 2 + 1) * SS + s) * DDIM;
  const float* xr = x + (size_t)row * DDIM;
  float v[12];
  float sm = 0.f, s2 = 0.f;
#pragma unroll
  for (int i = 0; i < 12; i++) {
    int d = i * 64 + lane;
    float m = y0r[d] + y1r[d] + tv0 * b2[e0 * DDIM + d] + tv1 * b2[e1 * DDIM + d];
    v[i] = m; sm += m; s2 += m * m;
  }
#pragma unroll
  for (int o = 32; o > 0; o >>= 1) { sm += __shfl_xor(sm, o); s2 += __shfl_xor(s2, o); }
  float mu = sm * (1.f / DDIM);
  float var = s2 * (1.f / DDIM) - mu * mu;
  float rs = rsqrtf(var + 1e-5f);
  float* orow = out + (size_t)row * DDIM;
#pragma unroll
  for (int i = 0; i < 12; i++) {
    int d = i * 64 + lane;
    orow[d] = xr[d] + (v[i] - mu) * rs * gamma[d] + beta[d];
  }
}

extern "C" void kernel_launch(void* const* d_in, const int* in_sizes, int n_in,
                              void* d_out, int out_size, void* d_ws, size_t ws_size,
                              hipStream_t stream) {
  const float* x     = (const float*)d_in[0];
  const float* text  = (const float*)d_in[1];
  const float* W1    = (const float*)d_in[2];
  const float* b1    = (const float*)d_in[3];
  const float* W2    = (const float*)d_in[4];
  const float* b2    = (const float*)d_in[5];
  const float* rw    = (const float*)d_in[6];
  const float* rb    = (const float*)d_in[7];
  const float* gamma = (const float*)d_in[8];
  const float* beta  = (const float*)d_in[9];
  float* out   = (float*)d_out;
  float* probs = out + (size_t)BB * SS * DDIM;

  char* ws = (char*)d_ws;
  int*   topi   = (int*)ws;
  float* topv   = (float*)(ws + 256);
  float* pooled = (float*)(ws + 512);
  size_t off = 25088;
  unsigned short* xb  = (unsigned short*)(ws + off);                 // 12.58 MB
  unsigned short* w1t = (unsigned short*)(ws + off + 12582912);      // 37.75 MB
  unsigned short* w2t = w1t + (size_t)EE * DDIM * FFF;               // 37.75 MB
  unsigned short* hbuf = w2t + (size_t)EE * DDIM * FFF;              // 100.66 MB
  float* yb = (float*)(ws + off);                                    // aliases xb+w1t

  prep_kernel<<<12480, 256, 0, stream>>>(W1, W2, x, w1t, w2t, xb, pooled);
  router_kernel<<<1, 1024, 0, stream>>>(pooled, text, rw, rb, probs, topi, topv);
  gemm_pipe<DDIM, 12, 48, true><<<768, 512, 0, stream>>>(
      w1t, xb, b1, topi, topv, hbuf, nullptr);
  gemm_pipe<FFF, 48, 12, false><<<192, 512, 0, stream>>>(
      w2t, hbuf, nullptr, topi, nullptr, nullptr, yb);
  ln_kernel<<<(BB * SS) / 4, 256, 0, stream>>>(x, yb, b2, topi, topv, gamma, beta, out);
}

// Round 2
// 469.735 us; speedup vs baseline: 1.1198x; 1.0102x over previous
//
#include <hip/hip_runtime.h>
#include <hip/hip_bf16.h>
#include <cstdint>
#include <cstddef>

#define BB 8
#define SS 1024
#define DDIM 768
#define FFF 3072
#define EE 8

typedef __attribute__((ext_vector_type(8))) short short8;
typedef __attribute__((ext_vector_type(4))) float f32x4;
typedef __attribute__((ext_vector_type(4))) unsigned short us4;

__device__ __forceinline__ unsigned short f2bf(float f) {
  unsigned u = __float_as_uint(f);
  u += 0x7FFFu + ((u >> 16) & 1u);
  return (unsigned short)(u >> 16);
}

__device__ __forceinline__ void async_ld16(const void* g, void* l) {
  __builtin_amdgcn_global_load_lds(
      (const __attribute__((address_space(1))) void*)g,
      (__attribute__((address_space(3))) void*)l, 16, 0, 0);
}

// ---------------- fused prep: tcast W1 | tcast W2 | cast x | pooled ----------------
__global__ __launch_bounds__(256) void prep_kernel(
    const float* __restrict__ W1, const float* __restrict__ W2,
    const float* __restrict__ x,
    unsigned short* __restrict__ w1t, unsigned short* __restrict__ w2t,
    unsigned short* __restrict__ xb, float* __restrict__ pooled) {
  __shared__ unsigned short tile[64 * 66 + 32];
  int blk = blockIdx.x;
  int t = threadIdx.x;
  if (blk < 9216) {
    const float* src; unsigned short* dst; int R, C, r0, c0;
    if (blk < 4608) {
      int e = blk / 576, rem = blk % 576;           // 12 r-tiles x 48 c-tiles
      r0 = (rem / 48) * 64; c0 = (rem % 48) * 64;
      src = W1 + (size_t)e * DDIM * FFF; dst = w1t + (size_t)e * FFF * DDIM;
      R = DDIM; C = FFF;
    } else {
      int b2 = blk - 4608;
      int e = b2 / 576, rem = b2 % 576;             // 48 r-tiles x 12 c-tiles
      r0 = (rem / 12) * 64; c0 = (rem % 12) * 64;
      src = W2 + (size_t)e * FFF * DDIM; dst = w2t + (size_t)e * DDIM * FFF;
      R = FFF; C = DDIM;
    }
    int row = t >> 4, c4 = (t & 15) * 4;
#pragma unroll
    for (int it = 0; it < 4; it++) {
      int r = row + it * 16;
      float4 v = *(const float4*)&src[(size_t)(r0 + r) * C + c0 + c4];
      us4 u; u[0] = f2bf(v.x); u[1] = f2bf(v.y); u[2] = f2bf(v.z); u[3] = f2bf(v.w);
      *(us4*)&tile[r * 66 + c4] = u;
    }
    __syncthreads();
    int seg = (t & 7) * 8;
#pragma unroll
    for (int it = 0; it < 2; it++) {
      int crow = it * 32 + (t >> 3);
      short8 u;
#pragma unroll
      for (int j = 0; j < 8; j++) u[j] = (short)tile[(seg + j) * 66 + crow];
      *(short8*)&dst[(size_t)(c0 + crow) * R + r0 + seg] = u;
    }
  } else if (blk < 12288) {
    size_t i = ((size_t)(blk - 9216) * 256 + t) * 8;
    float4 a = *(const float4*)&x[i];
    float4 b = *(const float4*)&x[i + 4];
    short8 u;
    u[0] = f2bf(a.x); u[1] = f2bf(a.y); u[2] = f2bf(a.z); u[3] = f2bf(a.w);
    u[4] = f2bf(b.x); u[5] = f2bf(b.y); u[6] = f2bf(b.z); u[7] = f2bf(b.w);
    *(short8*)&xb[i] = u;
  } else {
    float* red = (float*)tile;
    int blk2 = blk - 12288;
    int b = blk2 / 24, d0 = (blk2 % 24) * 32;
    int dl = t & 31, sg = t >> 5;
    const float* p = x + ((size_t)b * SS + sg) * DDIM + d0 + dl;
    float s = 0.f;
#pragma unroll 4
    for (int i = 0; i < SS / 8; i++) s += p[(size_t)i * 8 * DDIM];
    red[t] = s;
    __syncthreads();
    if (t < 32) {
      float acc = red[t];
#pragma unroll
      for (int g = 1; g < 8; g++) acc += red[g * 32 + t];
      pooled[b * DDIM + d0 + t] = acc * (1.f / SS);
    }
  }
}

// ---------------- router ----------------
__global__ void router_kernel(const float* __restrict__ pooled,
                              const float* __restrict__ text,
                              const float* __restrict__ rw,
                              const float* __restrict__ rb,
                              float* __restrict__ probs_out,
                              int* __restrict__ topi,
                              float* __restrict__ topv) {
  __shared__ float lg[BB * EE];
  int t = threadIdx.x;
  int be = t >> 4, part = t & 15;
  int b = be >> 3, e = be & 7;
  const float* pb = pooled + b * DDIM;
  const float* tb = text + b * DDIM;
  float acc = 0.f;
  int i0 = part * 96;
  for (int i = i0; i < i0 + 96; i++) {
    float f = (i < DDIM) ? pb[i] : tb[i - DDIM];
    acc += f * rw[i * EE + e];
  }
#pragma unroll
  for (int o = 8; o >= 1; o >>= 1) acc += __shfl_xor(acc, o);
  if (part == 0) lg[be] = acc + rb[e];
  __syncthreads();
  if (t < BB) {
    float p[EE];
    float mx = -1e30f;
    for (int e2 = 0; e2 < EE; e2++) { p[e2] = lg[t * EE + e2]; mx = fmaxf(mx, p[e2]); }
    float s = 0.f;
    for (int e2 = 0; e2 < EE; e2++) { p[e2] = expf(p[e2] - mx); s += p[e2]; }
    float inv = 1.f / s;
    for (int e2 = 0; e2 < EE; e2++) { p[e2] *= inv; probs_out[t * EE + e2] = p[e2]; }
    int j0 = 0; float v0 = p[0];
    for (int e2 = 1; e2 < EE; e2++) if (p[e2] > v0) { v0 = p[e2]; j0 = e2; }
    int j1 = -1; float v1 = -1e30f;
    for (int e2 = 0; e2 < EE; e2++) if (e2 != j0 && p[e2] > v1) { v1 = p[e2]; j1 = e2; }
    topi[t * 2] = j0; topi[t * 2 + 1] = j1;
    topv[t * 2] = v0; topv[t * 2 + 1] = v1;
  }
}

// shared MFMA phase macro: rows 2p,2p+1 x 4 j x 2 k-steps (16 MFMA)
#define PHASE(p, so_)                                                                      \
  do {                                                                                     \
    short8 a0k0 = *(const short8*)&sm[(so_) + aoff + (2 * (p)) * 1024 + ch0];              \
    short8 a0k1 = *(const short8*)&sm[(so_) + aoff + (2 * (p)) * 1024 + ch1];              \
    short8 a1k0 = *(const short8*)&sm[(so_) + aoff + (2 * (p) + 1) * 1024 + ch0];          \
    short8 a1k1 = *(const short8*)&sm[(so_) + aoff + (2 * (p) + 1) * 1024 + ch1];          \
    __builtin_amdgcn_s_setprio(1);                                                         \
    _Pragma("unroll") for (int j = 0; j < 4; j++) {                                        \
      acc[2 * (p)][j] =                                                                    \
          __builtin_amdgcn_mfma_f32_16x16x32_bf16(a0k0, bf[j][0], acc[2 * (p)][j], 0, 0, 0);   \
      acc[2 * (p)][j] =                                                                    \
          __builtin_amdgcn_mfma_f32_16x16x32_bf16(a0k1, bf[j][1], acc[2 * (p)][j], 0, 0, 0);   \
      acc[2 * (p) + 1][j] =                                                                \
          __builtin_amdgcn_mfma_f32_16x16x32_bf16(a1k0, bf[j][0], acc[2 * (p) + 1][j], 0, 0, 0); \
      acc[2 * (p) + 1][j] =                                                                \
          __builtin_amdgcn_mfma_f32_16x16x32_bf16(a1k1, bf[j][1], acc[2 * (p) + 1][j], 0, 0, 0); \
    }                                                                                      \
    __builtin_amdgcn_s_setprio(0);                                                         \
  } while (0)

#define READBF(so_)                                                        \
  do {                                                                     \
    _Pragma("unroll") for (int j = 0; j < 4; j++) {                        \
      bf[j][0] = *(const short8*)&sm[(so_) + boff + j * 1024 + ch0];       \
      bf[j][1] = *(const short8*)&sm[(so_) + boff + j * 1024 + ch1];       \
    }                                                                      \
  } while (0)

// ---------------- GEMM1: persistent, 256 blocks x 3 M-tiles of 256x256, K=768 ----------------
// LDS stage (ush): A[256x64] @0..16383, B[256x64] @16384..32767; stage stride 32768.
// bias: 768 f32 at ush offset 65536.
// Ledger: steady wait=vmcnt(4); first tile after an epilogue=vmcnt(0) (drains stores);
// very last tile=vmcnt(0).
__global__ __launch_bounds__(512, 2) void gemm1_pipe(
    const unsigned short* __restrict__ w1t,
    const unsigned short* __restrict__ xb,
    const float* __restrict__ b1,
    const int* __restrict__ topi,
    const float* __restrict__ topv,
    unsigned short* __restrict__ h) {
  int wg = (blockIdx.x & 7) * 32 + (blockIdx.x >> 3);  // XCD swizzle (256%8==0)
  int pair = wg >> 4;
  int sub = wg & 15;
  int Mg = sub >> 2;             // 0..3, each = 768 FF rows (3 tiles of 256)
  int N0 = (sub & 3) * 256;
  int e = topi[pair];
  float tv = topv[pair];
  const unsigned short* A = w1t + (size_t)e * DDIM * FFF + (size_t)Mg * 768 * DDIM;
  const unsigned short* B = xb + (size_t)(pair >> 1) * SS * DDIM + (size_t)N0 * DDIM;

  __shared__ unsigned short sm[65536 + 1536];
  float* biasLds = (float*)&sm[65536];
  int t = threadIdx.x;
  int lane = t & 63, wave = t >> 6;
  int wm = wave >> 2, wn = wave & 3;

  if (t < 192) {
    float4 bv = *(const float4*)&b1[e * FFF + Mg * 768 + t * 4];
    *(float4*)&biasLds[t * 4] = bv;
  }
  __syncthreads();  // drains vmcnt/lgkmcnt -> clean ledger before prologue

  int sr = t >> 3, c4 = t & 7;
  int gch = (c4 ^ (sr & 7)) * 8;  // pre-swizzled global source (T2)
  const unsigned short* gA = A + (size_t)sr * DDIM + gch;
  const unsigned short* gB = B + (size_t)sr * DDIM + gch;
  unsigned short* lds_t = sm + t * 8;

#define ISS1(gp, rofs, kk, uofs) \
  async_ld16((gp) + (size_t)(rofs) * DDIM + (kk), lds_t + (uofs))

  // prologue: A(0) x4, B(0) x4, B(1) x4
  ISS1(gA, 0, 0, 0); ISS1(gA, 64, 0, 4096); ISS1(gA, 128, 0, 8192); ISS1(gA, 192, 0, 12288);
  ISS1(gB, 0, 0, 16384); ISS1(gB, 64, 0, 20480); ISS1(gB, 128, 0, 24576); ISS1(gB, 192, 0, 28672);
  ISS1(gB, 0, 64, 49152); ISS1(gB, 64, 64, 53248); ISS1(gB, 128, 64, 57344); ISS1(gB, 192, 64, 61440);

  f32x4 acc[8][4];
#pragma unroll
  for (int i = 0; i < 8; i++)
#pragma unroll
    for (int j = 0; j < 4; j++) acc[i][j] = (f32x4){0.f, 0.f, 0.f, 0.f};

  int l15 = lane & 15, lg = lane >> 4, lx = lane & 7;
  int ch0 = (lg ^ lx) * 8;
  int ch1 = ((4 + lg) ^ lx) * 8;
  int aoff = wm * 8192 + l15 * 64;
  int boff = 16384 + wn * 4096 + l15 * 64;

#pragma unroll 1
  for (int mi = 0; mi < 3; mi++) {
    const unsigned short* gAm = gA + (size_t)mi * 256 * DDIM;
#pragma unroll 2
    for (int tt = 0; tt < 12; tt++) {
      int so = (tt & 1) << 15;
      int sn = so ^ 32768;
      // ---- wait + barrier ----
      if ((tt == 0 && mi > 0) || (mi == 2 && tt == 11))
        asm volatile("s_waitcnt vmcnt(0)" ::: "memory");
      else
        asm volatile("s_waitcnt vmcnt(4)" ::: "memory");
      __builtin_amdgcn_s_barrier();
      asm volatile("" ::: "memory");
      // ---- P1: issue A(v+1) u0,u1 ----
      bool haveA = !(mi == 2 && tt == 11);
      int ak = (tt < 11) ? (tt + 1) * 64 : 0;
      const unsigned short* gAn = (tt < 11) ? gAm : gAm + (size_t)256 * DDIM;
      if (haveA) { ISS1(gAn, 0, ak, sn); ISS1(gAn, 64, ak, sn + 4096); }
      short8 bf[4][2];
      READBF(so);
      PHASE(0, so);
      asm volatile("" ::: "memory");
      __builtin_amdgcn_s_barrier();  // frees this stage's B slots (bf in regs)
      asm volatile("" ::: "memory");
      // ---- P2 ----
      if (haveA) { ISS1(gAn, 128, ak, sn + 8192); ISS1(gAn, 192, ak, sn + 12288); }
      PHASE(1, so);
      // ---- P3: issue B(v+2) u0,u1 into current stage ----
      bool haveB = !(mi == 2 && tt >= 10);
      int bk = (tt < 10) ? (tt + 2) * 64 : (tt - 10) * 64;
      if (haveB) { ISS1(gB, 0, bk, so + 16384); ISS1(gB, 64, bk, so + 20480); }
      PHASE(2, so);
      // ---- P4 ----
      if (haveB) { ISS1(gB, 128, bk, so + 24576); ISS1(gB, 192, bk, so + 28672); }
      PHASE(3, so);
    }
    // ---- epilogue for M-tile mi (runs under in-flight next-tile loads) ----
    {
      int fb_loc = mi * 256 + wm * 128 + lg * 4;
      int fb0 = Mg * 768 + fb_loc;
      int sb0 = N0 + wn * 64 + l15;
      unsigned short* ho = h + (size_t)pair * SS * FFF;
      f32x4 bias[8];
#pragma unroll
      for (int i = 0; i < 8; i++)
        bias[i] = *(const f32x4*)&biasLds[fb_loc + i * 16];
#pragma unroll
      for (int j = 0; j < 4; j++) {
        int s = sb0 + j * 16;
#pragma unroll
        for (int i = 0; i < 8; i++) {
          us4 u;
#pragma unroll
          for (int r = 0; r < 4; r++) {
            float v = acc[i][j][r] + bias[i][r];
            float v2 = v * v;
            float u2 = v * (1.5957691216057308f + 0.07135481627f * v2);
            float ex = __expf(-u2);
            float g = v / (1.f + ex);
            u[r] = f2bf(g * tv);
          }
          *(us4*)&ho[(size_t)s * FFF + fb0 + i * 16] = u;
        }
      }
#pragma unroll
      for (int i = 0; i < 8; i++)
#pragma unroll
        for (int j = 0; j < 4; j++) acc[i][j] = (f32x4){0.f, 0.f, 0.f, 0.f};
    }
  }
#undef ISS1
}

// ---------------- GEMM2: 192x256 tiles -> exactly 256 blocks, K=3072 ----------------
// LDS stage (ush): A[192x64] @0..12287, B[256x64] @12288..28671; stage stride 28672.
// Wave-tile 96x64: acc[6][4]; 3 phases x 16 MFMA; per tile issue A x3 + B x4.
__global__ __launch_bounds__(512, 2) void gemm2_pipe(
    const unsigned short* __restrict__ w2t,
    const unsigned short* __restrict__ h,
    const int* __restrict__ topi,
    float* __restrict__ y) {
  int wg = (blockIdx.x & 7) * 32 + (blockIdx.x >> 3);  // XCD swizzle
  int pair = wg >> 4;
  int sub = wg & 15;
  int M0 = (sub >> 2) * 192;   // D tile (4 x 192 = 768)
  int N0 = (sub & 3) * 256;    // S tile
  int e = topi[pair];
  const unsigned short* A = w2t + (size_t)e * DDIM * FFF;
  const unsigned short* Bm = h + (size_t)pair * SS * FFF;

  __shared__ unsigned short sm[57344];
  int t = threadIdx.x;
  int lane = t & 63, wave = t >> 6;
  int wm = wave >> 2, wn = wave & 3;

  int sr = t >> 3, c4 = t & 7;
  int gch = (c4 ^ (sr & 7)) * 8;
  const unsigned short* gA = A + (size_t)(M0 + sr) * FFF + gch;
  const unsigned short* gB = Bm + (size_t)(N0 + sr) * FFF + gch;
  unsigned short* lds_t = sm + t * 8;

#define ISS2(gp, rofs, kk, uofs) \
  async_ld16((gp) + (size_t)(rofs) * FFF + (kk), lds_t + (uofs))

  // prologue: A(0) x3, B(0) x4, B(1) x4
  ISS2(gA, 0, 0, 0); ISS2(gA, 64, 0, 4096); ISS2(gA, 128, 0, 8192);
  ISS2(gB, 0, 0, 12288); ISS2(gB, 64, 0, 16384); ISS2(gB, 128, 0, 20480); ISS2(gB, 192, 0, 24576);
  ISS2(gB, 0, 64, 40960); ISS2(gB, 64, 64, 45056); ISS2(gB, 128, 64, 49152); ISS2(gB, 192, 64, 53248);

  f32x4 acc[6][4];
#pragma unroll
  for (int i = 0; i < 6; i++)
#pragma unroll
    for (int j = 0; j < 4; j++) acc[i][j] = (f32x4){0.f, 0.f, 0.f, 0.f};

  int l15 = lane & 15, lg = lane >> 4, lx = lane & 7;
  int ch0 = (lg ^ lx) * 8;
  int ch1 = ((4 + lg) ^ lx) * 8;
  int aoff = wm * 6144 + l15 * 64;
  int boff = 12288 + wn * 4096 + l15 * 64;

#pragma unroll 2
  for (int kt = 0; kt < 48; kt++) {
    int so = (kt & 1) * 28672;
    int sn = so ^ 28672;
    int kn = (kt + 1) * 64;
    int k2 = (kt + 2) * 64;
    if (kt == 47)
      asm volatile("s_waitcnt vmcnt(0)" ::: "memory");
    else
      asm volatile("s_waitcnt vmcnt(4)" ::: "memory");
    __builtin_amdgcn_s_barrier();
    asm volatile("" ::: "memory");
    // ---- P1: issue all of A(t+1) ----
    if (kt + 1 < 48) { ISS2(gA, 0, kn, sn); ISS2(gA, 64, kn, sn + 4096); ISS2(gA, 128, kn, sn + 8192); }
    short8 bf[4][2];
    READBF(so);
    PHASE(0, so);
    asm volatile("" ::: "memory");
    __builtin_amdgcn_s_barrier();  // frees this stage's B slots
    asm volatile("" ::: "memory");
    // ---- P2 ----
    if (kt + 2 < 48) { ISS2(gB, 0, k2, so + 12288); ISS2(gB, 64, k2, so + 16384); }
    PHASE(1, so);
    // ---- P3 ----
    if (kt + 2 < 48) { ISS2(gB, 128, k2, so + 20480); ISS2(gB, 192, k2, so + 24576); }
    PHASE(2, so);
  }
#undef ISS2

  int db0 = M0 + wm * 96 + lg * 4;
  int sb0 = N0 + wn * 64 + l15;
  float* yo = y + (size_t)pair * SS * DDIM;
#pragma unroll
  for (int j = 0; j < 4; j++) {
    int s = sb0 + j * 16;
#pragma unroll
    for (int i = 0; i < 6; i++)
      *(f32x4*)&yo[(size_t)s * DDIM + db0 + i * 16] = acc[i][j];
  }
}

// ---------------- LayerNorm + residual ----------------
__global__ void ln_kernel(const float* __restrict__ x,
                          const float* __restrict__ y,
                          const float* __restrict__ b2,
                          const int* __restrict__ topi,
                          const float* __restrict__ topv,
                          const float* __restrict__ gamma,
                          const float* __restrict__ beta,
                          float* __restrict__ out) {
  int wave = threadIdx.x >> 6, lane = threadIdx.x & 63;
  int row = blockIdx.x * 4 + wave;
  int b = row >> 10, s = row & 1023;
  int e0 = topi[b * 2], e1 = topi[b * 2 + 1];
  float tv0 = topv[b * 2], tv1 = topv[b * 2 + 1];
  const float* y0r = y + ((size_t)(b * 2) * SS + s) * DDIM;
  const float* y1r = y + ((size_t)(b * 2 + 1) * SS + s) * DDIM;
  const float* xr = x + (size_t)row * DDIM;
  float v[12];
  float sm = 0.f, s2 = 0.f;
#pragma unroll
  for (int i = 0; i < 12; i++) {
    int d = i * 64 + lane;
    float m = y0r[d] + y1r[d] + tv0 * b2[e0 * DDIM + d] + tv1 * b2[e1 * DDIM + d];
    v[i] = m; sm += m; s2 += m * m;
  }
#pragma unroll
  for (int o = 32; o > 0; o >>= 1) { sm += __shfl_xor(sm, o); s2 += __shfl_xor(s2, o); }
  float mu = sm * (1.f / DDIM);
  float var = s2 * (1.f / DDIM) - mu * mu;
  float rs = rsqrtf(var + 1e-5f);
  float* orow = out + (size_t)row * DDIM;
#pragma unroll
  for (int i = 0; i < 12; i++) {
    int d = i * 64 + lane;
    orow[d] = xr[d] + (v[i] - mu) * rs * gamma[d] + beta[d];
  }
}

extern "C" void kernel_launch(void* const* d_in, const int* in_sizes, int n_in,
                              void* d_out, int out_size, void* d_ws, size_t ws_size,
                              hipStream_t stream) {
  const float* x     = (const float*)d_in[0];
  const float* text  = (const float*)d_in[1];
  const float* W1    = (const float*)d_in[2];
  const float* b1    = (const float*)d_in[3];
  const float* W2    = (const float*)d_in[4];
  const float* b2    = (const float*)d_in[5];
  const float* rw    = (const float*)d_in[6];
  const float* rb    = (const float*)d_in[7];
  const float* gamma = (const float*)d_in[8];
  const float* beta  = (const float*)d_in[9];
  float* out   = (float*)d_out;
  float* probs = out + (size_t)BB * SS * DDIM;

  char* ws = (char*)d_ws;
  int*   topi   = (int*)ws;
  float* topv   = (float*)(ws + 256);
  float* pooled = (float*)(ws + 512);
  size_t off = 25088;
  unsigned short* xb  = (unsigned short*)(ws + off);                 // 12.58 MB
  unsigned short* w1t = (unsigned short*)(ws + off + 12582912);      // 37.75 MB
  unsigned short* w2t = w1t + (size_t)EE * DDIM * FFF;               // 37.75 MB
  unsigned short* hbuf = w2t + (size_t)EE * DDIM * FFF;              // 100.66 MB
  float* yb = (float*)(ws + off);                                    // aliases xb+w1t

  prep_kernel<<<12480, 256, 0, stream>>>(W1, W2, x, w1t, w2t, xb, pooled);
  router_kernel<<<1, 1024, 0, stream>>>(pooled, text, rw, rb, probs, topi, topv);
  gemm1_pipe<<<256, 512, 0, stream>>>(w1t, xb, b1, topi, topv, hbuf);
  gemm2_pipe<<<256, 512, 0, stream>>>(w2t, hbuf, topi, yb);
  ln_kernel<<<(BB * SS) / 4, 256, 0, stream>>>(x, yb, b2, topi, topv, gamma, beta, out);
}